// Round 4
// baseline (91012.305 us; speedup 1.0000x reference)
//
#include <hip/hip_runtime.h>
#include <hip/hip_bf16.h>

#define B_ 4
#define L_ 48
#define F_ 80
#define C_ 256
#define H_ 896
#define G3_ 2688
#define A_ 256
#define T_ 14400
#define NBLK_ 192
#define REP_ 75

// GRU geometry: 4 batches x 28 WGs x 8 waves = 224 waves/batch.
// Each wave owns 4 hidden units (3 gates x 4 rows = 12 rows), weights in VGPRs.
#define NMEM 28
#define RPW 12
#define FAST_TRY 24

typedef _Float16 __attribute__((ext_vector_type(8))) f16x8;
typedef __attribute__((ext_vector_type(4))) float f32x4;
typedef _Float16 __attribute__((ext_vector_type(2))) half2_;

__device__ __forceinline__ float fdot2f16(unsigned int a, unsigned int b, float c){
  return __builtin_amdgcn_fdot2(__builtin_bit_cast(half2_, a), __builtin_bit_cast(half2_, b), c, false);
}
__device__ __forceinline__ unsigned short f2h(float x){
  return __builtin_bit_cast(unsigned short, (_Float16)x);
}
__device__ __forceinline__ unsigned int packh2(float a, float b){
  return (unsigned int)f2h(a) | ((unsigned int)f2h(b) << 16);
}

// ---- wave-64 sum reduction via DPP. Total valid in lanes 48..63.
template<int CTRL>
__device__ __forceinline__ float dppadd(float x){
  int r = __builtin_amdgcn_update_dpp(0, __builtin_bit_cast(int, x), CTRL, 0xF, 0xF, true);
  return x + __builtin_bit_cast(float, r);
}
__device__ __forceinline__ float wred(float x){
  x = dppadd<0xB1>(x);   // quad_perm xor1
  x = dppadd<0x4E>(x);   // quad_perm xor2
  x = dppadd<0x124>(x);  // row_ror:4
  x = dppadd<0x128>(x);  // row_ror:8
  x = dppadd<0x142>(x);  // row_bcast:15
  x = dppadd<0x143>(x);  // row_bcast:31
  return x;
}

// 7 coalesced sc0 loads (bypass L1, served by this XCD's L2 when line is local)
__device__ __forceinline__ void ld7_sc0(const unsigned int* base, unsigned int* hd){
  asm volatile(
    "global_load_dword %0, %7, off sc0\n\t"
    "global_load_dword %1, %7, off offset:256 sc0\n\t"
    "global_load_dword %2, %7, off offset:512 sc0\n\t"
    "global_load_dword %3, %7, off offset:768 sc0\n\t"
    "global_load_dword %4, %7, off offset:1024 sc0\n\t"
    "global_load_dword %5, %7, off offset:1280 sc0\n\t"
    "global_load_dword %6, %7, off offset:1536 sc0\n\t"
    "s_waitcnt vmcnt(0)"
    : "=&v"(hd[0]), "=&v"(hd[1]), "=&v"(hd[2]), "=&v"(hd[3]),
      "=&v"(hd[4]), "=&v"(hd[5]), "=&v"(hd[6])
    : "v"(base)
    : "memory");
}

// ======================= prep kernels =======================
__global__ void k_transpose_pw(const float* __restrict__ pw, float* __restrict__ pwT){
  int idx = blockIdx.x * 256 + threadIdx.x;
  if (idx >= F_ * C_) return;
  int f = idx / C_, c = idx % C_;
  pwT[idx] = pw[c * F_ + f];
}

__global__ void k_x1(const float* __restrict__ lf, const float* __restrict__ pwT,
                     const float* __restrict__ pb, float* __restrict__ x1){
  int bl = blockIdx.x;
  int c = threadIdx.x;
  const float* lrow = lf + (size_t)bl * F_;
  float acc = pb[c];
  for (int f = 0; f < F_; ++f) acc = fmaf(lrow[f], pwT[f * C_ + c], acc);
  x1[(size_t)bl * C_ + c] = acc;
}

__global__ void k_transpose_up(const float* __restrict__ up, float* __restrict__ upT){
  int idx = blockIdx.x * 256 + threadIdx.x;   // 4*256*256
  int o = idx % C_, c = (idx / C_) % C_, k = idx / (C_ * C_);
  upT[idx] = up[(o * C_ + c) * 4 + k];
}

__global__ void k_cond(const float* __restrict__ upT, const float* __restrict__ x1,
                       const float* __restrict__ ub, float* __restrict__ cond){
  int bblk = blockIdx.x;
  int blk = bblk % NBLK_;
  int b = bblk / NBLK_;
  int l = blk >> 2, kk = blk & 3;
  int o = threadIdx.x;
  const float* x1row = x1 + ((size_t)b * L_ + l) * C_;
  const float* uT = upT + (size_t)kk * C_ * C_;
  float acc = ub[o];
  for (int c = 0; c < C_; ++c) acc = fmaf(x1row[c], uT[c * C_ + o], acc);
  cond[(size_t)bblk * C_ + o] = acc;
}

__global__ void k_transpose_wi(const float* __restrict__ wi, float* __restrict__ wiT){
  int idx = blockIdx.x * 256 + threadIdx.x;   // 256*2688
  int g = idx % G3_, c = idx / G3_;
  wiT[idx] = wi[(size_t)g * C_ + c];
}

__global__ void k_v(const float* __restrict__ wiT, const float* __restrict__ eb,
                    const float* __restrict__ cond, const float* __restrict__ bi,
                    float* __restrict__ v){
  int idx = blockIdx.x * 512 + threadIdx.x;   // 4*192*2688
  int g = idx % G3_;
  int bblk = idx / G3_;
  const float* crow = cond + (size_t)bblk * C_;
  float acc = bi[g];
  for (int c = 0; c < C_; ++c) acc = fmaf(eb[c] + crow[c], wiT[(size_t)c * G3_ + g], acc);
  v[idx] = acc;
}

__global__ void k_u(const float* __restrict__ wiT, const float* __restrict__ ew,
                    float* __restrict__ u){
  int g = blockIdx.x * 256 + threadIdx.x;
  if (g >= G3_) return;
  float acc = 0.f;
  for (int c = 0; c < C_; ++c) acc = fmaf(ew[c], wiT[(size_t)c * G3_ + g], acc);
  u[g] = acc;
}

// whp layout: [W=0..223][i=0..11][dw=0..6][lane=0..63] dwords (f16 pairs).
// Row (W,i): gate g=i>>2, hidden j=4W+(i&3) -> Wh row g*896 + 4W + (i&3).
// k-chunk for lane: pair index p = dw*64+lane, k = 2p  (matches coalesced
// h-dword layout: lane holds h dwords {lane, 64+lane, ..., 384+lane}).
__global__ void k_packwh(const float* __restrict__ wh, unsigned int* __restrict__ whp){
  int idx = blockIdx.x * 256 + threadIdx.x;   // 224*12*7*64 = 1,204,224
  int lane = idx & 63;
  int r2 = idx >> 6;
  int dw = r2 % 7; int r3 = r2 / 7;
  int i = r3 % RPW; int W = r3 / RPW;
  int g = (i >> 2) * H_ + W * 4 + (i & 3);
  int k = dw * 128 + lane * 2;
  const float* p = wh + (size_t)g * H_ + k;
  whp[idx] = packh2(p[0], p[1]);
}

__global__ void k_cvth(const float* __restrict__ src, unsigned short* __restrict__ dst, int n){
  int idx = blockIdx.x * 256 + threadIdx.x;
  if (idx >= n) return;
  dst[idx] = f2h(src[idx]);
}

// ======================= persistent GRU =======================
// hsx: [T+1][B][896] f16. Slot 0 = zeros (h0). Slots 1..T sentinel 0xFF
// (f2h(finite) never = 0xFFFF; h is bounded, never NaN; each dword written by
// exactly one lane). Producers: plain store (write-through -> local XCD L2)
// + relaxed agent atomic store of the SAME value to the SAME address (-> LLC).
// Fire-and-forget: no drains, no flags, no end-of-step barrier.
// Consumers: wave 0 polls the 448 h-dwords with coalesced sc0 loads (XCD-L2
// fast path); adaptively falls back to agent atomic loads (LLC, always
// correct) if the blockIdx->XCD placement heuristic doesn't hold. Grid 224:
// odd (bid&7) exit immediately so each batch's 28 workers share one XCD
// under round-robin dispatch (speed heuristic only — correctness never
// depends on placement).
__global__ __launch_bounds__(512, 2) void k_gru(
    const float* __restrict__ gold, const float* __restrict__ v,
    const float* __restrict__ u, const float* __restrict__ bh,
    const unsigned int* __restrict__ whp,
    unsigned short* hsx)
{
  const int bid = blockIdx.x;
  const int x = bid & 7;
  if (x & 1) return;                 // 112 trivial WGs keep XCD striping
  const int batch = x >> 1;
  const int m = bid >> 3;            // 0..27
  const int tid = threadIdx.x;
  const int wave = tid >> 6;
  const int lane = tid & 63;
  const int W = m * 8 + wave;        // 0..223: owns hidden units 4W..4W+3

  __shared__ unsigned int lds_h[2][448];

  // weight slice -> registers (84 dwords/lane)
  unsigned int wreg[RPW][7];
#pragma unroll
  for (int i = 0; i < RPW; ++i){
    const unsigned int* p = whp + ((size_t)(W * RPW + i) * 7) * 64 + lane;
#pragma unroll
    for (int dw = 0; dw < 7; ++dw) wreg[i][dw] = p[dw * 64];
  }

  const bool owner = (lane >= 48) && (lane < 52);
  const int jj = lane - 48;
  const int jg = 4 * W + (jj & 3);
  float u3[3] = {0,0,0}, bh3[3] = {0,0,0}, v3[3] = {0,0,0};
  float hcur = 0.f;
  if (owner){
    u3[0] = u[jg]; u3[1] = u[jg + H_]; u3[2] = u[jg + 2 * H_];
    bh3[0] = bh[jg]; bh3[1] = bh[jg + H_]; bh3[2] = bh[jg + 2 * H_];
  }
  const float* goldb = gold + (size_t)batch * T_;
  int cnt = 0, blkc = 0;
  int miss = 0;
  bool use_mirror = false;

  for (int t = 0; t < T_; ++t){
    unsigned int hd[7];
    if (wave == 0){
      const unsigned int* hp =
          (const unsigned int*)(hsx + ((size_t)t * B_ + batch) * H_) + lane;
      bool got = false;
      if (!use_mirror){
        for (int it = 0; it < FAST_TRY; ++it){
          ld7_sc0(hp, hd);
          bool ok = (hd[0] != ~0u) & (hd[1] != ~0u) & (hd[2] != ~0u) &
                    (hd[3] != ~0u) & (hd[4] != ~0u) & (hd[5] != ~0u) & (hd[6] != ~0u);
          if (__all(ok)){ got = true; break; }
        }
        if (!got && t >= 8 && ++miss >= 4) use_mirror = true;
      }
      if (!got){
        for (;;){
#pragma unroll
          for (int dw = 0; dw < 7; ++dw)
            hd[dw] = __hip_atomic_load(hp + dw * 64, __ATOMIC_RELAXED,
                                       __HIP_MEMORY_SCOPE_AGENT);
          bool ok = (hd[0] != ~0u) & (hd[1] != ~0u) & (hd[2] != ~0u) &
                    (hd[3] != ~0u) & (hd[4] != ~0u) & (hd[5] != ~0u) & (hd[6] != ~0u);
          if (__all(ok)) break;
        }
      }
#pragma unroll
      for (int dw = 0; dw < 7; ++dw) lds_h[t & 1][dw * 64 + lane] = hd[dw];
    }
    __syncthreads();
    if (wave != 0){
#pragma unroll
      for (int dw = 0; dw < 7; ++dw) hd[dw] = lds_h[t & 1][dw * 64 + lane];
    }

    // 12 row dots (3 gates x 4 j), reduced to lanes 48..63
    float acc[RPW];
#pragma unroll
    for (int i = 0; i < RPW; ++i){
      float a = 0.f;
#pragma unroll
      for (int dw = 0; dw < 7; ++dw) a = fdot2f16(wreg[i][dw], hd[dw], a);
      acc[i] = wred(a);
    }

    if (owner){
      float hr = jj==0 ? acc[0] : jj==1 ? acc[1] : jj==2 ? acc[2]  : acc[3];
      float hz = jj==0 ? acc[4] : jj==1 ? acc[5] : jj==2 ? acc[6]  : acc[7];
      float hn = jj==0 ? acc[8] : jj==1 ? acc[9] : jj==2 ? acc[10] : acc[11];
      hr += bh3[0]; hz += bh3[1]; hn += bh3[2];
      if (cnt == 0){
        const float* vp = v + ((size_t)(batch * NBLK_ + blkc)) * G3_ + jg;
        v3[0] = vp[0]; v3[1] = vp[H_]; v3[2] = vp[2 * H_];
      }
      float go = goldb[t];
      float xr = fmaf(go, u3[0], v3[0]);
      float xz = fmaf(go, u3[1], v3[1]);
      float xn = fmaf(go, u3[2], v3[2]);
      float r = 1.f / (1.f + __expf(-(xr + hr)));
      float z = 1.f / (1.f + __expf(-(xz + hz)));
      float e = __expf(2.f * (xn + r * hn));
      float n = 1.f - 2.f / (e + 1.f);          // tanh, inf-safe
      float hnew = (1.f - z) * n + z * hcur;
      hcur = hnew;
      // pack pairs via quad-perm DPP (lanes 48..51 form one quad)
      unsigned int h16 = (unsigned int)f2h(hnew);
      unsigned int oth = (unsigned int)__builtin_amdgcn_update_dpp(
          0, (int)h16, 0xB1, 0xF, 0xF, true);   // lane48<-49, lane50<-51
      if ((jj & 1) == 0){
        unsigned int packed = h16 | (oth << 16);
        unsigned int* dst = (unsigned int*)(hsx + ((size_t)(t + 1) * B_ + batch) * H_)
                          + 2 * W + (jj >> 1);
        // local-XCD copy (write-through L1 -> this XCD's L2); asm so it can't
        // be folded into the atomic below
        asm volatile("global_store_dword %0, %1, off" :: "v"(dst), "v"(packed) : "memory");
        // chip-visible mirror, same address same value (bypasses L2 -> LLC)
        __hip_atomic_store(dst, packed, __ATOMIC_RELAXED, __HIP_MEMORY_SCOPE_AGENT);
      }
    }
    if (++cnt == REP_){ cnt = 0; ++blkc; }
  }
}

// ======================= fused output MLP (MFMA f16) =======================
__global__ __launch_bounds__(256) void k_mlp(
    const unsigned short* hs, const unsigned short* __restrict__ w1h,
    const unsigned short* __restrict__ w2h, const float* __restrict__ ob1,
    const float* __restrict__ ob2, float* logits)
{
  const int mtile = blockIdx.x * 32;
  const int tid = threadIdx.x;
  const int wid = tid >> 6, lane = tid & 63;
  const int l15 = lane & 15, l4 = lane >> 4;
  __shared__ unsigned short y_lds[32 * 904];

  for (int nblk = 0; nblk < 14; ++nblk){
    f32x4 acc[2] = {(f32x4)(0.f), (f32x4)(0.f)};
    const int colg = nblk * 64 + wid * 16 + l15;
    for (int kk = 0; kk < 28; ++kk){
      const int k = kk * 32 + l4 * 8;
      f16x8 bfrag = *(const f16x8*)(w1h + (size_t)colg * H_ + k);
#pragma unroll
      for (int mf = 0; mf < 2; ++mf){
        f16x8 afrag = *(const f16x8*)(hs + (size_t)(mtile + mf * 16 + l15) * H_ + k);
        acc[mf] = __builtin_amdgcn_mfma_f32_16x16x32_f16(afrag, bfrag, acc[mf], 0, 0, 0);
      }
    }
    float bias = ob1[colg];
#pragma unroll
    for (int mf = 0; mf < 2; ++mf)
#pragma unroll
      for (int rg = 0; rg < 4; ++rg){
        float yv = acc[mf][rg] + bias;
        yv = yv > 0.f ? yv : 0.f;
        y_lds[(mf * 16 + l4 * 4 + rg) * 904 + colg] = f2h(yv);
      }
  }
  __syncthreads();

  f32x4 a2acc[2][4];
#pragma unroll
  for (int mf = 0; mf < 2; ++mf)
#pragma unroll
    for (int nf = 0; nf < 4; ++nf) a2acc[mf][nf] = (f32x4)(0.f);

  for (int kk = 0; kk < 28; ++kk){
    const int k = kk * 32 + l4 * 8;
    f16x8 a2[2];
#pragma unroll
    for (int mf = 0; mf < 2; ++mf)
      a2[mf] = *(const f16x8*)(&y_lds[(mf * 16 + l15) * 904 + k]);
#pragma unroll
    for (int nf = 0; nf < 4; ++nf){
      const int col = wid * 64 + nf * 16 + l15;
      f16x8 bfrag = *(const f16x8*)(w2h + (size_t)col * H_ + k);
#pragma unroll
      for (int mf = 0; mf < 2; ++mf)
        a2acc[mf][nf] = __builtin_amdgcn_mfma_f32_16x16x32_f16(a2[mf], bfrag, a2acc[mf][nf], 0, 0, 0);
    }
  }
#pragma unroll
  for (int nf = 0; nf < 4; ++nf){
    const int col = wid * 64 + nf * 16 + l15;
    const float bias = ob2[col];
#pragma unroll
    for (int mf = 0; mf < 2; ++mf)
#pragma unroll
      for (int rg = 0; rg < 4; ++rg){
        const int mrow = mtile + mf * 16 + l4 * 4 + rg;
        logits[(size_t)mrow * 448 + col] = a2acc[mf][nf][rg] + bias;
      }
  }
}

// ======================= log-softmax + transpose =======================
__global__ __launch_bounds__(256) void k_softmax(const float* __restrict__ logits,
                                                 float* __restrict__ out)
{
  const int bid = blockIdx.x;     // 900 = 4 * 225
  const int b = bid / 225;
  const int t0 = (bid % 225) * 64;
  const int tid = threadIdx.x;
  __shared__ float pm[64][4];
  __shared__ float ps[64][4];
  __shared__ float lz[64];
  {
    const int r = tid >> 2, q = tid & 3;
    const float* row = logits + (size_t)((t0 + r) * 4 + b) * 448 + q * 64;
    float mx = -1e30f;
    for (int j = 0; j < 64; ++j) mx = fmaxf(mx, row[j]);
    float s = 0.f;
    for (int j = 0; j < 64; ++j) s += __expf(row[j] - mx);
    pm[r][q] = mx; ps[r][q] = s;
  }
  __syncthreads();
  if (tid < 64){
    float m0 = pm[tid][0], m1 = pm[tid][1], m2 = pm[tid][2], m3 = pm[tid][3];
    float mx = fmaxf(fmaxf(m0, m1), fmaxf(m2, m3));
    float s = ps[tid][0] * __expf(m0 - mx) + ps[tid][1] * __expf(m1 - mx)
            + ps[tid][2] * __expf(m2 - mx) + ps[tid][3] * __expf(m3 - mx);
    lz[tid] = mx + logf(s);
  }
  __syncthreads();
  for (int i = 0; i < 64; ++i){
    const int idx = i * 256 + tid;
    const int a = idx >> 6, tt = idx & 63;
    float x = logits[(size_t)((t0 + tt) * 4 + b) * 448 + a];
    out[((size_t)(b * A_) + a) * T_ + t0 + tt] = x - lz[tt];
  }
}

// ======================= launcher =======================
extern "C" void kernel_launch(void* const* d_in, const int* in_sizes, int n_in,
                              void* d_out, int out_size, void* d_ws, size_t ws_size,
                              hipStream_t stream)
{
  (void)in_sizes; (void)n_in; (void)out_size; (void)ws_size;
  const float* lf   = (const float*)d_in[0];
  const float* gold = (const float*)d_in[1];
  const float* pw   = (const float*)d_in[2];
  const float* pb   = (const float*)d_in[3];
  const float* upw  = (const float*)d_in[4];
  const float* upb  = (const float*)d_in[5];
  const float* ew   = (const float*)d_in[6];
  const float* eb   = (const float*)d_in[7];
  const float* wi   = (const float*)d_in[8];
  const float* wh   = (const float*)d_in[9];
  const float* bi   = (const float*)d_in[10];
  const float* bhp  = (const float*)d_in[11];
  const float* w1   = (const float*)d_in[12];
  const float* b1   = (const float*)d_in[13];
  const float* w2   = (const float*)d_in[14];
  const float* b2   = (const float*)d_in[15];
  float* out = (float*)d_out;
  char* ws = (char*)d_ws;

  size_t off = 0;
  auto take = [&](size_t bytes){
    size_t r = off; off += (bytes + 255) & ~(size_t)255; return r;
  };
  float* pwT  = (float*)(ws + take((size_t)F_ * C_ * 4));
  float* x1   = (float*)(ws + take((size_t)B_ * L_ * C_ * 4));
  float* upT  = (float*)(ws + take((size_t)4 * C_ * C_ * 4));
  float* cond = (float*)(ws + take((size_t)B_ * NBLK_ * C_ * 4));
  float* wiT  = (float*)(ws + take((size_t)C_ * G3_ * 4));
  float* v    = (float*)(ws + take((size_t)B_ * NBLK_ * G3_ * 4));
  float* u    = (float*)(ws + take((size_t)G3_ * 4));
  unsigned int*   whp = (unsigned int*)(ws + take((size_t)224 * RPW * 7 * 64 * 4));
  unsigned short* w1h = (unsigned short*)(ws + take((size_t)H_ * H_ * 2));
  unsigned short* w2h = (unsigned short*)(ws + take((size_t)A_ * H_ * 2));
  unsigned short* hsx = (unsigned short*)(ws + take((size_t)(T_ + 1) * B_ * H_ * 2)); // 103 MB

  // per-launch state reset: slot 0 = h0 = 0; slots 1..T = 0xFF sentinel
  // (previous replay left real h values behind)
  hipMemsetAsync((void*)hsx, 0, (size_t)B_ * H_ * 2, stream);
  hipMemsetAsync((void*)(hsx + (size_t)B_ * H_), 0xFF, (size_t)T_ * B_ * H_ * 2, stream);

  k_transpose_pw<<<80, 256, 0, stream>>>(pw, pwT);
  k_x1<<<B_ * L_, 256, 0, stream>>>(lf, pwT, pb, x1);
  k_transpose_up<<<1024, 256, 0, stream>>>(upw, upT);
  k_cond<<<B_ * NBLK_, 256, 0, stream>>>(upT, x1, upb, cond);
  k_transpose_wi<<<2688, 256, 0, stream>>>(wi, wiT);
  k_v<<<4032, 512, 0, stream>>>(wiT, eb, cond, bi, v);
  k_u<<<11, 256, 0, stream>>>(wiT, ew, u);
  k_packwh<<<4704, 256, 0, stream>>>(wh, whp);
  k_cvth<<<(H_ * H_ + 255) / 256, 256, 0, stream>>>(w1, w1h, H_ * H_);
  k_cvth<<<(A_ * H_ + 255) / 256, 256, 0, stream>>>(w2, w2h, A_ * H_);

  k_gru<<<224, 512, 0, stream>>>(gold, v, u, bhp, whp, hsx);

  const unsigned short* hs_mlp = hsx + (size_t)B_ * H_;
  float* logits = (float*)hsx + (size_t)B_ * 448;
  k_mlp<<<1800, 256, 0, stream>>>(hs_mlp, w1h, w2h, b1, b2, logits);
  k_softmax<<<900, 256, 0, stream>>>(logits, out);
}

// Round 5
// 36033.310 us; speedup vs baseline: 2.5258x; 2.5258x over previous
//
#include <hip/hip_runtime.h>
#include <hip/hip_bf16.h>

#define B_ 4
#define L_ 48
#define F_ 80
#define C_ 256
#define H_ 896
#define G3_ 2688
#define A_ 256
#define T_ 14400
#define NBLK_ 192
#define REP_ 75

// GRU geometry: 4 batches x 28 WGs x 8 waves = 224 waves/batch.
// Each wave owns 4 hidden units (3 gates x 4 rows = 12 rows), weights in VGPRs.
#define NMEM 28
#define RPW 12

typedef _Float16 __attribute__((ext_vector_type(8))) f16x8;
typedef __attribute__((ext_vector_type(4))) float f32x4;
typedef _Float16 __attribute__((ext_vector_type(2))) half2_;

__device__ __forceinline__ float fdot2f16(unsigned int a, unsigned int b, float c){
  return __builtin_amdgcn_fdot2(__builtin_bit_cast(half2_, a), __builtin_bit_cast(half2_, b), c, false);
}
__device__ __forceinline__ unsigned short f2h(float x){
  return __builtin_bit_cast(unsigned short, (_Float16)x);
}
__device__ __forceinline__ unsigned int packh2(float a, float b){
  return (unsigned int)f2h(a) | ((unsigned int)f2h(b) << 16);
}

// ---- wave-64 sum reduction via DPP. Total valid in lanes 48..63.
template<int CTRL>
__device__ __forceinline__ float dppadd(float x){
  int r = __builtin_amdgcn_update_dpp(0, __builtin_bit_cast(int, x), CTRL, 0xF, 0xF, true);
  return x + __builtin_bit_cast(float, r);
}
__device__ __forceinline__ float wred(float x){
  x = dppadd<0xB1>(x);   // quad_perm xor1
  x = dppadd<0x4E>(x);   // quad_perm xor2
  x = dppadd<0x124>(x);  // row_ror:4
  x = dppadd<0x128>(x);  // row_ror:8
  x = dppadd<0x142>(x);  // row_bcast:15
  x = dppadd<0x143>(x);  // row_bcast:31
  return x;
}

// ======================= prep kernels =======================
__global__ void k_transpose_pw(const float* __restrict__ pw, float* __restrict__ pwT){
  int idx = blockIdx.x * 256 + threadIdx.x;
  if (idx >= F_ * C_) return;
  int f = idx / C_, c = idx % C_;
  pwT[idx] = pw[c * F_ + f];
}

__global__ void k_x1(const float* __restrict__ lf, const float* __restrict__ pwT,
                     const float* __restrict__ pb, float* __restrict__ x1){
  int bl = blockIdx.x;
  int c = threadIdx.x;
  const float* lrow = lf + (size_t)bl * F_;
  float acc = pb[c];
  for (int f = 0; f < F_; ++f) acc = fmaf(lrow[f], pwT[f * C_ + c], acc);
  x1[(size_t)bl * C_ + c] = acc;
}

__global__ void k_transpose_up(const float* __restrict__ up, float* __restrict__ upT){
  int idx = blockIdx.x * 256 + threadIdx.x;   // 4*256*256
  int o = idx % C_, c = (idx / C_) % C_, k = idx / (C_ * C_);
  upT[idx] = up[(o * C_ + c) * 4 + k];
}

__global__ void k_cond(const float* __restrict__ upT, const float* __restrict__ x1,
                       const float* __restrict__ ub, float* __restrict__ cond){
  int bblk = blockIdx.x;
  int blk = bblk % NBLK_;
  int b = bblk / NBLK_;
  int l = blk >> 2, kk = blk & 3;
  int o = threadIdx.x;
  const float* x1row = x1 + ((size_t)b * L_ + l) * C_;
  const float* uT = upT + (size_t)kk * C_ * C_;
  float acc = ub[o];
  for (int c = 0; c < C_; ++c) acc = fmaf(x1row[c], uT[c * C_ + o], acc);
  cond[(size_t)bblk * C_ + o] = acc;
}

__global__ void k_transpose_wi(const float* __restrict__ wi, float* __restrict__ wiT){
  int idx = blockIdx.x * 256 + threadIdx.x;   // 256*2688
  int g = idx % G3_, c = idx / G3_;
  wiT[idx] = wi[(size_t)g * C_ + c];
}

__global__ void k_v(const float* __restrict__ wiT, const float* __restrict__ eb,
                    const float* __restrict__ cond, const float* __restrict__ bi,
                    float* __restrict__ v){
  int idx = blockIdx.x * 512 + threadIdx.x;   // 4*192*2688
  int g = idx % G3_;
  int bblk = idx / G3_;
  const float* crow = cond + (size_t)bblk * C_;
  float acc = bi[g];
  for (int c = 0; c < C_; ++c) acc = fmaf(eb[c] + crow[c], wiT[(size_t)c * G3_ + g], acc);
  v[idx] = acc;
}

__global__ void k_u(const float* __restrict__ wiT, const float* __restrict__ ew,
                    float* __restrict__ u){
  int g = blockIdx.x * 256 + threadIdx.x;
  if (g >= G3_) return;
  float acc = 0.f;
  for (int c = 0; c < C_; ++c) acc = fmaf(ew[c], wiT[(size_t)c * G3_ + g], acc);
  u[g] = acc;
}

// whp layout: [W=0..223][i=0..11][dw=0..6][lane=0..63] dwords (f16 pairs).
// Row (W,i): gate g=i>>2, hidden j=4W+(i&3) -> Wh row g*896 + 4W + (i&3).
// k-chunk for lane: pair index p = dw*64+lane, k = 2p  (matches coalesced
// h-dword layout: lane holds h dwords {lane, 64+lane, ..., 384+lane}).
__global__ void k_packwh(const float* __restrict__ wh, unsigned int* __restrict__ whp){
  int idx = blockIdx.x * 256 + threadIdx.x;   // 224*12*7*64 = 1,204,224
  int lane = idx & 63;
  int r2 = idx >> 6;
  int dw = r2 % 7; int r3 = r2 / 7;
  int i = r3 % RPW; int W = r3 / RPW;
  int g = (i >> 2) * H_ + W * 4 + (i & 3);
  int k = dw * 128 + lane * 2;
  const float* p = wh + (size_t)g * H_ + k;
  whp[idx] = packh2(p[0], p[1]);
}

__global__ void k_cvth(const float* __restrict__ src, unsigned short* __restrict__ dst, int n){
  int idx = blockIdx.x * 256 + threadIdx.x;
  if (idx >= n) return;
  dst[idx] = f2h(src[idx]);
}

// ======================= persistent GRU =======================
// hsx: [T+1][B][896] f16. Slot 0 = zeros (h0). Slots 1..T sentinel 0xFF
// (f2h(finite) never = 0xFFFF; h bounded, never NaN; each dword written by
// exactly ONE atomic dword store -> no tearing). Producers: ONE relaxed agent
// atomic store, fire-and-forget — no drains, no counters, no end barrier.
// Consumers: wave 0 polls the 448 h-dwords of slot t with 7 coalesced relaxed
// agent atomic loads (28 lines/WG/iter, s_sleep backoff) — detect and fetch
// are the same LLC hop — then broadcasts via LDS.
__global__ __launch_bounds__(512, 2) void k_gru(
    const float* __restrict__ gold, const float* __restrict__ v,
    const float* __restrict__ u, const float* __restrict__ bh,
    const unsigned int* __restrict__ whp,
    unsigned short* hsx)
{
  const int bid = blockIdx.x;
  const int batch = (bid & 7) >> 1;                 // XCD-affinity heuristic only
  const int m = ((bid >> 3) << 1) | (bid & 1);      // 0..27
  const int tid = threadIdx.x;
  const int wave = tid >> 6;
  const int lane = tid & 63;
  const int W = m * 8 + wave;                       // 0..223: owns hidden units 4W..4W+3

  __shared__ unsigned int lds_h[2][448];

  // weight slice -> registers (84 dwords/lane)
  unsigned int wreg[RPW][7];
#pragma unroll
  for (int i = 0; i < RPW; ++i){
    const unsigned int* p = whp + ((size_t)(W * RPW + i) * 7) * 64 + lane;
#pragma unroll
    for (int dw = 0; dw < 7; ++dw) wreg[i][dw] = p[dw * 64];
  }

  const bool owner = (lane >= 48) && (lane < 52);
  const int jj = lane - 48;
  const int jg = 4 * W + (jj & 3);
  float u3[3] = {0,0,0}, bh3[3] = {0,0,0}, v3[3] = {0,0,0}, v3n[3] = {0,0,0};
  float hcur = 0.f;
  if (owner){
    u3[0] = u[jg]; u3[1] = u[jg + H_]; u3[2] = u[jg + 2 * H_];
    bh3[0] = bh[jg]; bh3[1] = bh[jg + H_]; bh3[2] = bh[jg + 2 * H_];
    const float* vp = v + ((size_t)(batch * NBLK_)) * G3_ + jg;   // block 0
    v3[0] = vp[0]; v3[1] = vp[H_]; v3[2] = vp[2 * H_];
  }
  const float* goldb = gold + (size_t)batch * T_;
  int cnt = 0, blkc = 0;

  for (int t = 0; t < T_; ++t){
    float go = goldb[t];            // hoisted: latency hides under the poll
    unsigned int hd[7];
    if (wave == 0){
      const unsigned int* hp =
          (const unsigned int*)(hsx + ((size_t)t * B_ + batch) * H_) + lane;
      for (;;){
#pragma unroll
        for (int dw = 0; dw < 7; ++dw)
          hd[dw] = __hip_atomic_load(hp + dw * 64, __ATOMIC_RELAXED,
                                     __HIP_MEMORY_SCOPE_AGENT);
        bool ok = (hd[0] != ~0u) & (hd[1] != ~0u) & (hd[2] != ~0u) &
                  (hd[3] != ~0u) & (hd[4] != ~0u) & (hd[5] != ~0u) & (hd[6] != ~0u);
        if (__all(ok)) break;
        __builtin_amdgcn_s_sleep(1);
      }
#pragma unroll
      for (int dw = 0; dw < 7; ++dw) lds_h[t & 1][dw * 64 + lane] = hd[dw];
    }
    __syncthreads();
    if (wave != 0){
#pragma unroll
      for (int dw = 0; dw < 7; ++dw) hd[dw] = lds_h[t & 1][dw * 64 + lane];
    }

    // 12 row dots (3 gates x 4 j), reduced to lanes 48..63
    float acc[RPW];
#pragma unroll
    for (int i = 0; i < RPW; ++i){
      float a = 0.f;
#pragma unroll
      for (int dw = 0; dw < 7; ++dw) a = fdot2f16(wreg[i][dw], hd[dw], a);
      acc[i] = wred(a);
    }

    if (owner){
      // prefetch next v-block 2 steps early (off the critical path)
      if (cnt == REP_ - 2){
        int nb = blkc + 1; if (nb > NBLK_ - 1) nb = NBLK_ - 1;
        const float* vp = v + ((size_t)(batch * NBLK_ + nb)) * G3_ + jg;
        v3n[0] = vp[0]; v3n[1] = vp[H_]; v3n[2] = vp[2 * H_];
      }
      float hr = jj==0 ? acc[0] : jj==1 ? acc[1] : jj==2 ? acc[2]  : acc[3];
      float hz = jj==0 ? acc[4] : jj==1 ? acc[5] : jj==2 ? acc[6]  : acc[7];
      float hn = jj==0 ? acc[8] : jj==1 ? acc[9] : jj==2 ? acc[10] : acc[11];
      hr += bh3[0]; hz += bh3[1]; hn += bh3[2];
      float xr = fmaf(go, u3[0], v3[0]);
      float xz = fmaf(go, u3[1], v3[1]);
      float xn = fmaf(go, u3[2], v3[2]);
      float r = 1.f / (1.f + __expf(-(xr + hr)));
      float z = 1.f / (1.f + __expf(-(xz + hz)));
      float e = __expf(2.f * (xn + r * hn));
      float n = 1.f - 2.f / (e + 1.f);          // tanh, inf-safe
      float hnew = (1.f - z) * n + z * hcur;
      hcur = hnew;
      // pack pairs via quad-perm DPP (lanes 48..51 form one quad)
      unsigned int h16 = (unsigned int)f2h(hnew);
      unsigned int oth = (unsigned int)__builtin_amdgcn_update_dpp(
          0, (int)h16, 0xB1, 0xF, 0xF, true);   // lane48<-49, lane50<-51
      if ((jj & 1) == 0){
        unsigned int packed = h16 | (oth << 16);
        unsigned int* dst = (unsigned int*)(hsx + ((size_t)(t + 1) * B_ + batch) * H_)
                          + 2 * W + (jj >> 1);
        __hip_atomic_store(dst, packed, __ATOMIC_RELAXED, __HIP_MEMORY_SCOPE_AGENT);
      }
    }
    if (++cnt == REP_){
      cnt = 0; ++blkc;
      v3[0] = v3n[0]; v3[1] = v3n[1]; v3[2] = v3n[2];
    }
  }
}

// ======================= fused output MLP (MFMA f16) =======================
__global__ __launch_bounds__(256) void k_mlp(
    const unsigned short* hs, const unsigned short* __restrict__ w1h,
    const unsigned short* __restrict__ w2h, const float* __restrict__ ob1,
    const float* __restrict__ ob2, float* logits)
{
  const int mtile = blockIdx.x * 32;
  const int tid = threadIdx.x;
  const int wid = tid >> 6, lane = tid & 63;
  const int l15 = lane & 15, l4 = lane >> 4;
  __shared__ unsigned short y_lds[32 * 904];

  for (int nblk = 0; nblk < 14; ++nblk){
    f32x4 acc[2] = {(f32x4)(0.f), (f32x4)(0.f)};
    const int colg = nblk * 64 + wid * 16 + l15;
    for (int kk = 0; kk < 28; ++kk){
      const int k = kk * 32 + l4 * 8;
      f16x8 bfrag = *(const f16x8*)(w1h + (size_t)colg * H_ + k);
#pragma unroll
      for (int mf = 0; mf < 2; ++mf){
        f16x8 afrag = *(const f16x8*)(hs + (size_t)(mtile + mf * 16 + l15) * H_ + k);
        acc[mf] = __builtin_amdgcn_mfma_f32_16x16x32_f16(afrag, bfrag, acc[mf], 0, 0, 0);
      }
    }
    float bias = ob1[colg];
#pragma unroll
    for (int mf = 0; mf < 2; ++mf)
#pragma unroll
      for (int rg = 0; rg < 4; ++rg){
        float yv = acc[mf][rg] + bias;
        yv = yv > 0.f ? yv : 0.f;
        y_lds[(mf * 16 + l4 * 4 + rg) * 904 + colg] = f2h(yv);
      }
  }
  __syncthreads();

  f32x4 a2acc[2][4];
#pragma unroll
  for (int mf = 0; mf < 2; ++mf)
#pragma unroll
    for (int nf = 0; nf < 4; ++nf) a2acc[mf][nf] = (f32x4)(0.f);

  for (int kk = 0; kk < 28; ++kk){
    const int k = kk * 32 + l4 * 8;
    f16x8 a2[2];
#pragma unroll
    for (int mf = 0; mf < 2; ++mf)
      a2[mf] = *(const f16x8*)(&y_lds[(mf * 16 + l15) * 904 + k]);
#pragma unroll
    for (int nf = 0; nf < 4; ++nf){
      const int col = wid * 64 + nf * 16 + l15;
      f16x8 bfrag = *(const f16x8*)(w2h + (size_t)col * H_ + k);
#pragma unroll
      for (int mf = 0; mf < 2; ++mf)
        a2acc[mf][nf] = __builtin_amdgcn_mfma_f32_16x16x32_f16(a2[mf], bfrag, a2acc[mf][nf], 0, 0, 0);
    }
  }
#pragma unroll
  for (int nf = 0; nf < 4; ++nf){
    const int col = wid * 64 + nf * 16 + l15;
    const float bias = ob2[col];
#pragma unroll
    for (int mf = 0; mf < 2; ++mf)
#pragma unroll
      for (int rg = 0; rg < 4; ++rg){
        const int mrow = mtile + mf * 16 + l4 * 4 + rg;
        logits[(size_t)mrow * 448 + col] = a2acc[mf][nf][rg] + bias;
      }
  }
}

// ======================= log-softmax + transpose =======================
__global__ __launch_bounds__(256) void k_softmax(const float* __restrict__ logits,
                                                 float* __restrict__ out)
{
  const int bid = blockIdx.x;     // 900 = 4 * 225
  const int b = bid / 225;
  const int t0 = (bid % 225) * 64;
  const int tid = threadIdx.x;
  __shared__ float pm[64][4];
  __shared__ float ps[64][4];
  __shared__ float lz[64];
  {
    const int r = tid >> 2, q = tid & 3;
    const float* row = logits + (size_t)((t0 + r) * 4 + b) * 448 + q * 64;
    float mx = -1e30f;
    for (int j = 0; j < 64; ++j) mx = fmaxf(mx, row[j]);
    float s = 0.f;
    for (int j = 0; j < 64; ++j) s += __expf(row[j] - mx);
    pm[r][q] = mx; ps[r][q] = s;
  }
  __syncthreads();
  if (tid < 64){
    float m0 = pm[tid][0], m1 = pm[tid][1], m2 = pm[tid][2], m3 = pm[tid][3];
    float mx = fmaxf(fmaxf(m0, m1), fmaxf(m2, m3));
    float s = ps[tid][0] * __expf(m0 - mx) + ps[tid][1] * __expf(m1 - mx)
            + ps[tid][2] * __expf(m2 - mx) + ps[tid][3] * __expf(m3 - mx);
    lz[tid] = mx + logf(s);
  }
  __syncthreads();
  for (int i = 0; i < 64; ++i){
    const int idx = i * 256 + tid;
    const int a = idx >> 6, tt = idx & 63;
    float x = logits[(size_t)((t0 + tt) * 4 + b) * 448 + a];
    out[((size_t)(b * A_) + a) * T_ + t0 + tt] = x - lz[tt];
  }
}

// ======================= launcher =======================
extern "C" void kernel_launch(void* const* d_in, const int* in_sizes, int n_in,
                              void* d_out, int out_size, void* d_ws, size_t ws_size,
                              hipStream_t stream)
{
  (void)in_sizes; (void)n_in; (void)out_size; (void)ws_size;
  const float* lf   = (const float*)d_in[0];
  const float* gold = (const float*)d_in[1];
  const float* pw   = (const float*)d_in[2];
  const float* pb   = (const float*)d_in[3];
  const float* upw  = (const float*)d_in[4];
  const float* upb  = (const float*)d_in[5];
  const float* ew   = (const float*)d_in[6];
  const float* eb   = (const float*)d_in[7];
  const float* wi   = (const float*)d_in[8];
  const float* wh   = (const float*)d_in[9];
  const float* bi   = (const float*)d_in[10];
  const float* bhp  = (const float*)d_in[11];
  const float* w1   = (const float*)d_in[12];
  const float* b1   = (const float*)d_in[13];
  const float* w2   = (const float*)d_in[14];
  const float* b2   = (const float*)d_in[15];
  float* out = (float*)d_out;
  char* ws = (char*)d_ws;

  size_t off = 0;
  auto take = [&](size_t bytes){
    size_t r = off; off += (bytes + 255) & ~(size_t)255; return r;
  };
  float* pwT  = (float*)(ws + take((size_t)F_ * C_ * 4));
  float* x1   = (float*)(ws + take((size_t)B_ * L_ * C_ * 4));
  float* upT  = (float*)(ws + take((size_t)4 * C_ * C_ * 4));
  float* cond = (float*)(ws + take((size_t)B_ * NBLK_ * C_ * 4));
  float* wiT  = (float*)(ws + take((size_t)C_ * G3_ * 4));
  float* v    = (float*)(ws + take((size_t)B_ * NBLK_ * G3_ * 4));
  float* u    = (float*)(ws + take((size_t)G3_ * 4));
  unsigned int*   whp = (unsigned int*)(ws + take((size_t)224 * RPW * 7 * 64 * 4));
  unsigned short* w1h = (unsigned short*)(ws + take((size_t)H_ * H_ * 2));
  unsigned short* w2h = (unsigned short*)(ws + take((size_t)A_ * H_ * 2));
  unsigned short* hsx = (unsigned short*)(ws + take((size_t)(T_ + 1) * B_ * H_ * 2)); // 103 MB

  // per-launch state reset: slot 0 = h0 = 0; slots 1..T = 0xFF sentinel
  // (previous replay left real h values behind)
  hipMemsetAsync((void*)hsx, 0, (size_t)B_ * H_ * 2, stream);
  hipMemsetAsync((void*)(hsx + (size_t)B_ * H_), 0xFF, (size_t)T_ * B_ * H_ * 2, stream);

  k_transpose_pw<<<80, 256, 0, stream>>>(pw, pwT);
  k_x1<<<B_ * L_, 256, 0, stream>>>(lf, pwT, pb, x1);
  k_transpose_up<<<1024, 256, 0, stream>>>(upw, upT);
  k_cond<<<B_ * NBLK_, 256, 0, stream>>>(upT, x1, upb, cond);
  k_transpose_wi<<<2688, 256, 0, stream>>>(wi, wiT);
  k_v<<<4032, 512, 0, stream>>>(wiT, eb, cond, bi, v);
  k_u<<<11, 256, 0, stream>>>(wiT, ew, u);
  k_packwh<<<4704, 256, 0, stream>>>(wh, whp);
  k_cvth<<<(H_ * H_ + 255) / 256, 256, 0, stream>>>(w1, w1h, H_ * H_);
  k_cvth<<<(A_ * H_ + 255) / 256, 256, 0, stream>>>(w2, w2h, A_ * H_);

  k_gru<<<112, 512, 0, stream>>>(gold, v, u, bhp, whp, hsx);

  const unsigned short* hs_mlp = hsx + (size_t)B_ * H_;
  float* logits = (float*)hsx + (size_t)B_ * 448;
  k_mlp<<<1800, 256, 0, stream>>>(hs_mlp, w1h, w2h, b1, b2, logits);
  k_softmax<<<900, 256, 0, stream>>>(logits, out);
}